// Round 5
// baseline (591.099 us; speedup 1.0000x reference)
//
#include <hip/hip_runtime.h>
#include <math.h>

namespace {
constexpr int B_   = 8;
constexpr int DIM_ = 2048;
constexpr int H_   = 16;
constexpr int QLR_ = 1536;
constexpr int KVLR_= 512;
constexpr int DN_  = 128;
constexpr int DR_  = 64;
constexpr int DV_  = 128;
constexpr int TPRE_= 8191;
constexpr int CE_  = 576;    // KVLR + DR
constexpr int NCH_ = 64;     // chunks over T=8192
constexpr int CT_  = 128;    // t per chunk
constexpr int TT_  = 8;      // t per LDS tile
constexpr int NTILE_ = CT_ / TT_; // 16
constexpr int RSTR_ = 584;   // LDS tile row stride in floats (576 data + 8 pad)
constexpr float EPS_ = 1e-6f;
constexpr float SCALE_ = 0.07216878364870322f; // (DN+DR)^-0.5

// workspace layout (float offsets)
constexpr size_t WS_QLAT  = 0;
constexpr size_t WS_KVPE  = WS_QLAT  + (size_t)B_*QLR_;
constexpr size_t WS_KVNEW = WS_KVPE  + (size_t)B_*CE_;
constexpr size_t WS_PENEW = WS_KVNEW + (size_t)B_*KVLR_;
constexpr size_t WS_QRS   = WS_PENEW + (size_t)B_*DR_;
constexpr size_t WS_QNOPE = WS_QRS   + (size_t)B_;
constexpr size_t WS_QT    = WS_QNOPE + (size_t)B_*H_*DN_;   // [b][h][576]
constexpr size_t WS_MLOC  = WS_QT    + (size_t)B_*H_*CE_;
constexpr size_t WS_LLOC  = WS_MLOC  + (size_t)B_*H_*NCH_;
constexpr size_t WS_OUT2  = WS_LLOC  + (size_t)B_*H_*NCH_;
constexpr size_t WS_OPART = WS_OUT2  + (size_t)B_*DIM_;     // [b][h][chunk][512]
} // namespace

// ---------------- K1: q_latent = x@wq_a^T + b ; kvpe = x@wkv_a^T + b ----------------
__global__ __launch_bounds__(256) void mla_k1(const float* __restrict__ x,
                                              const float* __restrict__ wqa,
                                              const float* __restrict__ bqa,
                                              const float* __restrict__ wkva,
                                              const float* __restrict__ bkva,
                                              float* __restrict__ ws) {
  const int w = threadIdx.x >> 6, l = threadIdx.x & 63;
  const int r = blockIdx.x * 4 + w;  // 0..2111
  const float* W; const float* bias; float* out; int rr; int ostride;
  if (r < QLR_) { W = wqa;  bias = bqa;  out = ws + WS_QLAT; rr = r;        ostride = QLR_; }
  else          { W = wkva; bias = bkva; out = ws + WS_KVPE; rr = r - QLR_; ostride = CE_;  }
  const float4* wp = (const float4*)(W + (size_t)rr * DIM_);
  const float4* x4 = (const float4*)x;
  float4 wv[8];
#pragma unroll
  for (int j = 0; j < 8; ++j) wv[j] = wp[l + 64 * j];
  float acc[B_];
#pragma unroll
  for (int b = 0; b < B_; ++b) acc[b] = 0.f;
#pragma unroll
  for (int b = 0; b < B_; ++b) {
#pragma unroll
    for (int j = 0; j < 8; ++j) {
      const float4 xv = x4[b * (DIM_ / 4) + l + 64 * j];
      acc[b] = fmaf(wv[j].x, xv.x, fmaf(wv[j].y, xv.y, fmaf(wv[j].z, xv.z, fmaf(wv[j].w, xv.w, acc[b]))));
    }
  }
#pragma unroll
  for (int b = 0; b < B_; ++b)
#pragma unroll
    for (int s = 32; s; s >>= 1) acc[b] += __shfl_xor(acc[b], s);
  if (l == 0) {
    const float b0 = bias[rr];
#pragma unroll
    for (int b = 0; b < B_; ++b) out[b * ostride + rr] = acc[b] + b0;
  }
}

// ---------------- K2: kv rms-norm + k_pe rope + q rms scales ----------------
__global__ __launch_bounds__(256) void mla_k2(const float* __restrict__ kvnw,
                                              const float* __restrict__ fcos,
                                              const float* __restrict__ fsin,
                                              float* __restrict__ ws) {
  const int tid = threadIdx.x;
  const int b = tid >> 5, i = tid & 31;
  const float* kvpe = ws + WS_KVPE + b * CE_;
  float ss = 0.f;
#pragma unroll
  for (int j = 0; j < KVLR_ / 32; ++j) { const float v = kvpe[i + 32 * j]; ss = fmaf(v, v, ss); }
#pragma unroll
  for (int s = 16; s; s >>= 1) ss += __shfl_xor(ss, s, 32);
  const float scale = 1.0f / sqrtf(ss / (float)KVLR_ + EPS_);
  float* kvn = ws + WS_KVNEW + b * KVLR_;
#pragma unroll
  for (int j = 0; j < KVLR_ / 32; ++j) {
    const int c = i + 32 * j;
    kvn[c] = kvpe[c] * kvnw[c] * scale;
  }
  {
    const float xr = kvpe[KVLR_ + 2 * i], xi = kvpe[KVLR_ + 2 * i + 1];
    const float c = fcos[i], s = fsin[i];
    float* pen = ws + WS_PENEW + b * DR_;
    pen[2 * i]     = xr * c - xi * s;
    pen[2 * i + 1] = xr * s + xi * c;
  }
  {
    const float* p = ws + WS_QLAT + b * QLR_;
    float sq = 0.f;
#pragma unroll
    for (int j = 0; j < QLR_ / 32; ++j) { const float v = p[i + 32 * j]; sq = fmaf(v, v, sq); }
#pragma unroll
    for (int s = 16; s; s >>= 1) sq += __shfl_xor(sq, s, 32);
    if (i == 0) ws[WS_QRS + b] = 1.0f / sqrtf(sq / (float)QLR_ + EPS_);
  }
}

// ---------------- K3: q = rms(q_lat)*g @ wq_b^T + b ; split nope / rope(pe) ----------------
__global__ __launch_bounds__(256) void mla_k3(const float* __restrict__ qnw,
                                              const float* __restrict__ wqb,
                                              const float* __restrict__ bqb,
                                              const float* __restrict__ fcos,
                                              const float* __restrict__ fsin,
                                              float* __restrict__ ws) {
  const int w = threadIdx.x >> 6, l = threadIdx.x & 63;
  const int r0 = blockIdx.x * 8 + w * 2;  // 0..3070
  const float4* w0p = (const float4*)(wqb + (size_t)r0 * QLR_);
  const float4* w1p = (const float4*)(wqb + (size_t)(r0 + 1) * QLR_);
  const float4* g4  = (const float4*)qnw;
  const float4* x4  = (const float4*)(ws + WS_QLAT);
  float4 wg0[6], wg1[6];
#pragma unroll
  for (int j = 0; j < 6; ++j) {
    const int c4 = l + 64 * j;
    const float4 a = w0p[c4], bb = w1p[c4], g = g4[c4];
    wg0[j].x = a.x * g.x; wg0[j].y = a.y * g.y; wg0[j].z = a.z * g.z; wg0[j].w = a.w * g.w;
    wg1[j].x = bb.x * g.x; wg1[j].y = bb.y * g.y; wg1[j].z = bb.z * g.z; wg1[j].w = bb.w * g.w;
  }
  float acc0[B_], acc1[B_];
#pragma unroll
  for (int b = 0; b < B_; ++b) { acc0[b] = 0.f; acc1[b] = 0.f; }
#pragma unroll
  for (int b = 0; b < B_; ++b) {
#pragma unroll
    for (int j = 0; j < 6; ++j) {
      const float4 xv = x4[b * (QLR_ / 4) + l + 64 * j];
      acc0[b] = fmaf(wg0[j].x, xv.x, fmaf(wg0[j].y, xv.y, fmaf(wg0[j].z, xv.z, fmaf(wg0[j].w, xv.w, acc0[b]))));
      acc1[b] = fmaf(wg1[j].x, xv.x, fmaf(wg1[j].y, xv.y, fmaf(wg1[j].z, xv.z, fmaf(wg1[j].w, xv.w, acc1[b]))));
    }
  }
#pragma unroll
  for (int b = 0; b < B_; ++b)
#pragma unroll
    for (int s = 32; s; s >>= 1) {
      acc0[b] += __shfl_xor(acc0[b], s);
      acc1[b] += __shfl_xor(acc1[b], s);
    }
  if (l == 0) {
    const int h = r0 / (DN_ + DR_);
    const int j0 = r0 - h * (DN_ + DR_);
    const float b0 = bqb[r0], b1 = bqb[r0 + 1];
    if (j0 < DN_) {
      float* qn = ws + WS_QNOPE;
#pragma unroll
      for (int b = 0; b < B_; ++b) {
        const float sb = ws[WS_QRS + b];
        qn[(b * H_ + h) * DN_ + j0]     = acc0[b] * sb + b0;
        qn[(b * H_ + h) * DN_ + j0 + 1] = acc1[b] * sb + b1;
      }
    } else {
      const int i = (j0 - DN_) >> 1;
      const float c = fcos[i], s = fsin[i];
      float* qT = ws + WS_QT;
#pragma unroll
      for (int b = 0; b < B_; ++b) {
        const float sb = ws[WS_QRS + b];
        const float xr = acc0[b] * sb + b0, xi = acc1[b] * sb + b1;
        qT[((size_t)b * H_ + h) * CE_ + KVLR_ + 2 * i]     = xr * c - xi * s;
        qT[((size_t)b * H_ + h) * CE_ + KVLR_ + 2 * i + 1] = xr * s + xi * c;
      }
    }
  }
}

// ---------------- K4: q_abs[b][h][c] = sum_d q_nope[b][h][d] * wkv_b[h][d][c] ----------------
__global__ __launch_bounds__(256) void mla_k4(const float* __restrict__ wkvb,
                                              float* __restrict__ ws) {
  __shared__ float red[7 * 32 * B_];
  const int h = blockIdx.y;
  const int strip = blockIdx.x;     // 16 strips of 32 cols
  const int tid = threadIdx.x;
  const int c = tid & 31, dg = tid >> 5;  // 8 groups of 16 d
  const int cg = strip * 32 + c;
  const float* qn = ws + WS_QNOPE;
  float acc[B_];
#pragma unroll
  for (int b = 0; b < B_; ++b) acc[b] = 0.f;
  const float* wp = wkvb + (size_t)h * 256 * KVLR_ + cg;
#pragma unroll
  for (int dd = 0; dd < 16; ++dd) {
    const int d = dg * 16 + dd;
    const float wv = wp[(size_t)d * KVLR_];
#pragma unroll
    for (int b = 0; b < B_; ++b) acc[b] = fmaf(qn[(b * H_ + h) * DN_ + d], wv, acc[b]);
  }
  if (dg > 0) {
#pragma unroll
    for (int b = 0; b < B_; ++b) red[(((dg - 1) * 32) + c) * B_ + b] = acc[b];
  }
  __syncthreads();
  if (dg == 0) {
    float* qT = ws + WS_QT;
#pragma unroll
    for (int b = 0; b < B_; ++b) {
      float v = acc[b];
#pragma unroll
      for (int g = 0; g < 7; ++g) v += red[(g * 32 + c) * B_ + b];
      qT[((size_t)b * H_ + h) * CE_ + cg] = v;
    }
  }
}

// ---------------- K5: double-buffered coalesced flash decode per (b, chunk of 128) ----------------
__global__ __launch_bounds__(256, 3) void mla_k5(const float* __restrict__ kvpre,
                                                 const float* __restrict__ pepre,
                                                 float* __restrict__ ws) {
  __shared__ float buf[2][TT_ * RSTR_];           // 2 x 18.2 KB (kv 512 + pe 64 packed per row)
  __shared__ float sc[TT_ * 20];                  // scores -> p  [t][h pad 20]
  __shared__ __align__(16) float mrun[H_], lrun[H_], alf[H_];
  const int b = blockIdx.y, chunk = blockIdx.x;
  const int t0 = chunk * CT_;
  const int tid = threadIdx.x;
  const int l = tid & 63, w = tid >> 6;
  // scores map: thread = (head, c-slice of 36)
  const int h_s = tid >> 4, sl = tid & 15;
  // accum map: wave = (chalf, head-half), lane = c-quad
  const int chalf = w & 1, hh = w >> 1;
  const float* kvnewb = ws + WS_KVNEW + b * KVLR_;
  const float* penewb = ws + WS_PENEW + b * DR_;

  if (tid < H_) { mrun[tid] = -3.4e38f; lrun[tid] = 0.f; }

  // persistent q fragment: q[b][h_s][sl*36 .. +35]
  float4 qreg[9];
  {
    const float* qp = ws + WS_QT + ((size_t)b * H_ + h_s) * CE_ + sl * 36;
#pragma unroll
    for (int i = 0; i < 9; ++i) qreg[i] = *(const float4*)(qp + 4 * i);
  }
  float4 o[8];
#pragma unroll
  for (int a = 0; a < 8; ++a) { o[a].x = 0.f; o[a].y = 0.f; o[a].z = 0.f; o[a].w = 0.f; }

  float4 kvr[4]; float4 per;
  auto issue = [&](int tbase) {
#pragma unroll
    for (int k = 0; k < 4; ++k) {
      const int idx = tid + 256 * k;
      const int row = idx >> 7, c4 = idx & 127;
      const int tg = tbase + row;
      const float* src = (tg < TPRE_) ? (kvpre + ((size_t)b * TPRE_ + tg) * KVLR_ + c4 * 4)
                                      : (kvnewb + c4 * 4);
      kvr[k] = *(const float4*)src;
    }
    if (tid < 128) {
      const int row = tid >> 4, c4 = tid & 15;
      const int tg = tbase + row;
      const float* src = (tg < TPRE_) ? (pepre + ((size_t)b * TPRE_ + tg) * DR_ + c4 * 4)
                                      : (penewb + c4 * 4);
      per = *(const float4*)src;
    }
  };
  auto commit = [&](float* dst) {
#pragma unroll
    for (int k = 0; k < 4; ++k) {
      const int idx = tid + 256 * k;
      const int row = idx >> 7, c4 = idx & 127;
      *(float4*)(dst + row * RSTR_ + c4 * 4) = kvr[k];
    }
    if (tid < 128) {
      const int row = tid >> 4, c4 = tid & 15;
      *(float4*)(dst + row * RSTR_ + 512 + c4 * 4) = per;
    }
  };

  issue(t0);
  commit(buf[0]);
  __syncthreads();

  for (int j = 0; j < NTILE_; ++j) {
    const int cur = j & 1;
    if (j < NTILE_ - 1) issue(t0 + (j + 1) * TT_);   // in flight during scores
    const float* bp = buf[cur];
    // ---- scores ----
#pragma unroll
    for (int tt = 0; tt < TT_; ++tt) {
      const float* kp = bp + tt * RSTR_ + sl * 36;
      float4 s4; s4.x = 0.f; s4.y = 0.f; s4.z = 0.f; s4.w = 0.f;
#pragma unroll
      for (int i = 0; i < 9; ++i) {
        const float4 kv = *(const float4*)(kp + 4 * i);
        s4.x = fmaf(kv.x, qreg[i].x, s4.x);
        s4.y = fmaf(kv.y, qreg[i].y, s4.y);
        s4.z = fmaf(kv.z, qreg[i].z, s4.z);
        s4.w = fmaf(kv.w, qreg[i].w, s4.w);
      }
      float s = (s4.x + s4.y) + (s4.z + s4.w);
      s += __shfl_xor(s, 1); s += __shfl_xor(s, 2);
      s += __shfl_xor(s, 4); s += __shfl_xor(s, 8);
      if (sl == 0) sc[tt * 20 + h_s] = s * SCALE_;
    }
    __syncthreads();
    // ---- online softmax (tid<128): thread = (h, t) ----
    if (tid < 128) {
      const int hm = tid >> 3, tm = tid & 7;
      const float s = sc[tm * 20 + hm];
      float mt = s;
      mt = fmaxf(mt, __shfl_xor(mt, 1));
      mt = fmaxf(mt, __shfl_xor(mt, 2));
      mt = fmaxf(mt, __shfl_xor(mt, 4));
      const float mprev = mrun[hm];
      const float mnew = fmaxf(mprev, mt);
      const float p = __expf(s - mnew);
      sc[tm * 20 + hm] = p;
      float ls = p;
      ls += __shfl_xor(ls, 1); ls += __shfl_xor(ls, 2); ls += __shfl_xor(ls, 4);
      if (tm == 0) {
        const float a = __expf(mprev - mnew);
        alf[hm] = a;
        lrun[hm] = lrun[hm] * a + ls;
        mrun[hm] = mnew;
      }
    }
    __syncthreads();
    // ---- accumulate o from LDS tile ----
    {
      const float4 a0 = *(const float4*)(alf + hh * 8);
      const float4 a1 = *(const float4*)(alf + hh * 8 + 4);
      o[0].x *= a0.x; o[0].y *= a0.x; o[0].z *= a0.x; o[0].w *= a0.x;
      o[1].x *= a0.y; o[1].y *= a0.y; o[1].z *= a0.y; o[1].w *= a0.y;
      o[2].x *= a0.z; o[2].y *= a0.z; o[2].z *= a0.z; o[2].w *= a0.z;
      o[3].x *= a0.w; o[3].y *= a0.w; o[3].z *= a0.w; o[3].w *= a0.w;
      o[4].x *= a1.x; o[4].y *= a1.x; o[4].z *= a1.x; o[4].w *= a1.x;
      o[5].x *= a1.y; o[5].y *= a1.y; o[5].z *= a1.y; o[5].w *= a1.y;
      o[6].x *= a1.z; o[6].y *= a1.z; o[6].z *= a1.z; o[6].w *= a1.z;
      o[7].x *= a1.w; o[7].y *= a1.w; o[7].z *= a1.w; o[7].w *= a1.w;
#pragma unroll
      for (int tt = 0; tt < TT_; ++tt) {
        const float4 kv = *(const float4*)(bp + tt * RSTR_ + chalf * 256 + 4 * l);
        const float4 p0 = *(const float4*)(sc + tt * 20 + hh * 8);
        const float4 p1 = *(const float4*)(sc + tt * 20 + hh * 8 + 4);
        o[0].x = fmaf(p0.x, kv.x, o[0].x); o[0].y = fmaf(p0.x, kv.y, o[0].y);
        o[0].z = fmaf(p0.x, kv.z, o[0].z); o[0].w = fmaf(p0.x, kv.w, o[0].w);
        o[1].x = fmaf(p0.y, kv.x, o[1].x); o[1].y = fmaf(p0.y, kv.y, o[1].y);
        o[1].z = fmaf(p0.y, kv.z, o[1].z); o[1].w = fmaf(p0.y, kv.w, o[1].w);
        o[2].x = fmaf(p0.z, kv.x, o[2].x); o[2].y = fmaf(p0.z, kv.y, o[2].y);
        o[2].z = fmaf(p0.z, kv.z, o[2].z); o[2].w = fmaf(p0.z, kv.w, o[2].w);
        o[3].x = fmaf(p0.w, kv.x, o[3].x); o[3].y = fmaf(p0.w, kv.y, o[3].y);
        o[3].z = fmaf(p0.w, kv.z, o[3].z); o[3].w = fmaf(p0.w, kv.w, o[3].w);
        o[4].x = fmaf(p1.x, kv.x, o[4].x); o[4].y = fmaf(p1.x, kv.y, o[4].y);
        o[4].z = fmaf(p1.x, kv.z, o[4].z); o[4].w = fmaf(p1.x, kv.w, o[4].w);
        o[5].x = fmaf(p1.y, kv.x, o[5].x); o[5].y = fmaf(p1.y, kv.y, o[5].y);
        o[5].z = fmaf(p1.y, kv.z, o[5].z); o[5].w = fmaf(p1.y, kv.w, o[5].w);
        o[6].x = fmaf(p1.z, kv.x, o[6].x); o[6].y = fmaf(p1.z, kv.y, o[6].y);
        o[6].z = fmaf(p1.z, kv.z, o[6].z); o[6].w = fmaf(p1.z, kv.w, o[6].w);
        o[7].x = fmaf(p1.w, kv.x, o[7].x); o[7].y = fmaf(p1.w, kv.y, o[7].y);
        o[7].z = fmaf(p1.w, kv.z, o[7].z); o[7].w = fmaf(p1.w, kv.w, o[7].w);
      }
    }
    if (j < NTILE_ - 1) commit(buf[1 - cur]);
    __syncthreads();
  }
  // ---- write partials ----
#pragma unroll
  for (int a = 0; a < 8; ++a) {
    const int h = hh * 8 + a;
    *(float4*)(ws + WS_OPART + (((size_t)(b * H_ + h) * NCH_ + chunk) * KVLR_) + chalf * 256 + 4 * l) = o[a];
  }
  if (tid < H_) {
    ws[WS_MLOC + (b * H_ + tid) * NCH_ + chunk] = mrun[tid];
    ws[WS_LLOC + (b * H_ + tid) * NCH_ + chunk] = lrun[tid];
  }
}

// ---------------- K6: combine partials + project through wkv_b[:,128:,:] ----------------
__global__ __launch_bounds__(256) void mla_k6(const float* __restrict__ wkvb,
                                              float* __restrict__ ws) {
  const int h = blockIdx.x, b = blockIdx.y;
  __shared__ float wgt[NCH_];
  __shared__ float ao[KVLR_];
  __shared__ float Linv;
  const int tid = threadIdx.x;
  if (tid < NCH_) { // one full wave (NCH_ == 64)
    const float m = ws[WS_MLOC + (b * H_ + h) * NCH_ + tid];
    float M = m;
#pragma unroll
    for (int s = 32; s; s >>= 1) M = fmaxf(M, __shfl_xor(M, s));
    const float wv = __expf(m - M);
    wgt[tid] = wv;
    float lv = ws[WS_LLOC + (b * H_ + h) * NCH_ + tid] * wv;
#pragma unroll
    for (int s = 32; s; s >>= 1) lv += __shfl_xor(lv, s);
    if (tid == 0) Linv = 1.0f / lv;
  }
  __syncthreads();
  const float* Ob = ws + WS_OPART + (size_t)(b * H_ + h) * NCH_ * KVLR_;
  float s0 = 0.f, s1 = 0.f;
#pragma unroll 4
  for (int i = 0; i < NCH_; ++i) {
    const float wv = wgt[i];
    s0 = fmaf(wv, Ob[(size_t)i * KVLR_ + tid], s0);
    s1 = fmaf(wv, Ob[(size_t)i * KVLR_ + tid + 256], s1);
  }
  const float li = Linv;
  ao[tid] = s0 * li;
  ao[tid + 256] = s1 * li;
  __syncthreads();
  const int v = tid >> 1, half = tid & 1;
  const float* w2 = wkvb + ((size_t)h * 256 + DN_ + v) * KVLR_ + half * 256;
  const float* a = ao + half * 256;
  float s = 0.f;
#pragma unroll
  for (int c = 0; c < 256; c += 4) {
    const float4 wv = *(const float4*)(w2 + c);
    s = fmaf(wv.x, a[c], s);
    s = fmaf(wv.y, a[c + 1], s);
    s = fmaf(wv.z, a[c + 2], s);
    s = fmaf(wv.w, a[c + 3], s);
  }
  s += __shfl_xor(s, 1);
  if (half == 0) ws[WS_OUT2 + b * DIM_ + h * DV_ + v] = s;
}

// ---------------- K7: y = out2 @ wo^T + wo_b ----------------
__global__ __launch_bounds__(256) void mla_k7(const float* __restrict__ wo,
                                              const float* __restrict__ wob,
                                              const float* __restrict__ ws,
                                              float* __restrict__ out) {
  const int w = threadIdx.x >> 6, l = threadIdx.x & 63;
  const int r = blockIdx.x * 4 + w;  // 0..2047
  const float4* wp = (const float4*)(wo + (size_t)r * DIM_);
  const float4* x4 = (const float4*)(ws + WS_OUT2);
  float4 wv[8];
#pragma unroll
  for (int j = 0; j < 8; ++j) wv[j] = wp[l + 64 * j];
  float acc[B_];
#pragma unroll
  for (int b = 0; b < B_; ++b) acc[b] = 0.f;
#pragma unroll
  for (int b = 0; b < B_; ++b) {
#pragma unroll
    for (int j = 0; j < 8; ++j) {
      const float4 xv = x4[b * (DIM_ / 4) + l + 64 * j];
      acc[b] = fmaf(wv[j].x, xv.x, fmaf(wv[j].y, xv.y, fmaf(wv[j].z, xv.z, fmaf(wv[j].w, xv.w, acc[b]))));
    }
  }
#pragma unroll
  for (int b = 0; b < B_; ++b)
#pragma unroll
    for (int s = 32; s; s >>= 1) acc[b] += __shfl_xor(acc[b], s);
  if (l == 0) {
    const float b0 = wob[r];
#pragma unroll
    for (int b = 0; b < B_; ++b) out[b * DIM_ + r] = acc[b] + b0;
  }
}

extern "C" void kernel_launch(void* const* d_in, const int* in_sizes, int n_in,
                              void* d_out, int out_size, void* d_ws, size_t ws_size,
                              hipStream_t stream) {
  (void)in_sizes; (void)n_in; (void)out_size; (void)ws_size;
  const float* x     = (const float*)d_in[0];
  const float* fcos  = (const float*)d_in[2];
  const float* fsin  = (const float*)d_in[3];
  const float* kvpre = (const float*)d_in[4];
  const float* pepre = (const float*)d_in[5];
  const float* wqa   = (const float*)d_in[6];
  const float* bqa   = (const float*)d_in[7];
  const float* qnw   = (const float*)d_in[8];
  const float* wqb   = (const float*)d_in[9];
  const float* bqb   = (const float*)d_in[10];
  const float* wkva  = (const float*)d_in[11];
  const float* bkva  = (const float*)d_in[12];
  const float* kvnw  = (const float*)d_in[13];
  const float* wkvb  = (const float*)d_in[14];
  const float* wo    = (const float*)d_in[15];
  const float* wob   = (const float*)d_in[16];
  float* ws  = (float*)d_ws;
  float* out = (float*)d_out;

  mla_k1<<<dim3((QLR_ + CE_) / 4), dim3(256), 0, stream>>>(x, wqa, bqa, wkva, bkva, ws);
  mla_k2<<<dim3(1), dim3(256), 0, stream>>>(kvnw, fcos, fsin, ws);
  mla_k3<<<dim3(H_ * (DN_ + DR_) / 8), dim3(256), 0, stream>>>(qnw, wqb, bqb, fcos, fsin, ws);
  mla_k4<<<dim3(16, H_), dim3(256), 0, stream>>>(wkvb, ws);
  mla_k5<<<dim3(NCH_, B_), dim3(256), 0, stream>>>(kvpre, pepre, ws);
  mla_k6<<<dim3(H_, B_), dim3(256), 0, stream>>>(wkvb, ws);
  mla_k7<<<dim3(DIM_ / 4), dim3(256), 0, stream>>>(wo, wob, ws, out);
}